// Round 1
// baseline (334.947 us; speedup 1.0000x reference)
//
#include <hip/hip_runtime.h>
#include <math.h>

#define TOKENS 16384
#define DMODEL 2048
#define NEXP   64
#define TOPK   8
#define BM     64
#define BK     32

// Kernel 1: logits[t][e] = sum_d x[t][d] * W[e][d] + b[e]
// Classic LDS-tiled fp32 GEMM, 64x64 tile per 256-thread block, 4x4 register
// tile per thread. fp32 FMA chunks of 8 flushed into fp64 accumulators for
// numpy-grade accuracy (top-k index stability).
__global__ __launch_bounds__(256) void router_gemm(
    const float* __restrict__ x, const float* __restrict__ W,
    const float* __restrict__ bias, float* __restrict__ logits)
{
    __shared__ float xs[BM][BK + 1];   // pad +1: staging writes / reads <=2-way
    __shared__ float ws[BK][NEXP + 1];

    const int tid = threadIdx.x;
    const int kq  = tid & 7;    // which float4 along K
    const int row = tid >> 3;   // 0..31 (token row / expert row for staging)
    const int ty  = tid >> 4;   // 0..15 token group (4 tokens each)
    const int tx  = tid & 15;   // 0..15 expert group (4 experts each)
    const size_t tokBase = (size_t)blockIdx.x * BM;

    double accd[4][4];
    float  accf[4][4];
#pragma unroll
    for (int i = 0; i < 4; ++i)
#pragma unroll
        for (int j = 0; j < 4; ++j) { accd[i][j] = 0.0; accf[i][j] = 0.0f; }

    for (int k0 = 0; k0 < DMODEL; k0 += BK) {
        const float4 xa = *(const float4*)(x + (tokBase + row) * DMODEL + k0 + kq * 4);
        const float4 xb = *(const float4*)(x + (tokBase + row + 32) * DMODEL + k0 + kq * 4);
        const float4 wa = *(const float4*)(W + (size_t)row * DMODEL + k0 + kq * 4);
        const float4 wb = *(const float4*)(W + (size_t)(row + 32) * DMODEL + k0 + kq * 4);
        __syncthreads();   // previous tile's readers done before overwrite
        xs[row][kq * 4 + 0] = xa.x; xs[row][kq * 4 + 1] = xa.y;
        xs[row][kq * 4 + 2] = xa.z; xs[row][kq * 4 + 3] = xa.w;
        xs[row + 32][kq * 4 + 0] = xb.x; xs[row + 32][kq * 4 + 1] = xb.y;
        xs[row + 32][kq * 4 + 2] = xb.z; xs[row + 32][kq * 4 + 3] = xb.w;
        ws[kq * 4 + 0][row] = wa.x; ws[kq * 4 + 1][row] = wa.y;
        ws[kq * 4 + 2][row] = wa.z; ws[kq * 4 + 3][row] = wa.w;
        ws[kq * 4 + 0][row + 32] = wb.x; ws[kq * 4 + 1][row + 32] = wb.y;
        ws[kq * 4 + 2][row + 32] = wb.z; ws[kq * 4 + 3][row + 32] = wb.w;
        __syncthreads();

#pragma unroll
        for (int kk = 0; kk < BK; ++kk) {
            float a[4], bb[4];
#pragma unroll
            for (int i = 0; i < 4; ++i) a[i] = xs[ty * 4 + i][kk];
#pragma unroll
            for (int j = 0; j < 4; ++j) bb[j] = ws[kk][tx * 4 + j];
#pragma unroll
            for (int i = 0; i < 4; ++i)
#pragma unroll
                for (int j = 0; j < 4; ++j)
                    accf[i][j] = fmaf(a[i], bb[j], accf[i][j]);
            if ((kk & 7) == 7) {   // flush fp32 chunk into fp64 accumulator
#pragma unroll
                for (int i = 0; i < 4; ++i)
#pragma unroll
                    for (int j = 0; j < 4; ++j) {
                        accd[i][j] += (double)accf[i][j];
                        accf[i][j] = 0.0f;
                    }
            }
        }
    }

#pragma unroll
    for (int i = 0; i < 4; ++i) {
        const size_t tok = tokBase + ty * 4 + i;
#pragma unroll
        for (int j = 0; j < 4; ++j) {
            const int e = tx * 4 + j;
            logits[tok * NEXP + e] = (float)accd[i][j] + bias[e];
        }
    }
}

// Kernel 2: per-token top-8 (descending, ties -> lower index, matching
// jax.lax.top_k), sigmoid on the selected values. One thread per token,
// logit rows staged through padded LDS so the per-thread row walk is
// conflict-free.
__global__ __launch_bounds__(256) void router_topk(
    const float* __restrict__ logits, float* __restrict__ out_w,
    float* __restrict__ out_i)
{
    __shared__ float sl[256][NEXP + 1];
    const int tid = threadIdx.x;
    const size_t tb = (size_t)blockIdx.x * 256;

#pragma unroll
    for (int it = 0; it < 16; ++it) {
        const int idx = it * 256 + tid;       // float4 index in 256x64 tile
        const int t   = idx >> 4;
        const int e0  = (idx & 15) * 4;
        const float4 v = *(const float4*)(logits + tb * NEXP + (size_t)idx * 4);
        sl[t][e0 + 0] = v.x; sl[t][e0 + 1] = v.y;
        sl[t][e0 + 2] = v.z; sl[t][e0 + 3] = v.w;
    }
    __syncthreads();

    float bv[TOPK];
    int   bi[TOPK];
#pragma unroll
    for (int q = 0; q < TOPK; ++q) { bv[q] = -INFINITY; bi[q] = 0; }

    for (int e = 0; e < NEXP; ++e) {
        const float v = sl[tid][e];
        if (v > bv[TOPK - 1]) {        // strict >: equal keeps earlier index
            bool g[TOPK];
#pragma unroll
            for (int q = 0; q < TOPK; ++q) g[q] = v > bv[q];
#pragma unroll
            for (int q = TOPK - 1; q >= 1; --q) {
                bv[q] = g[q] ? (g[q - 1] ? bv[q - 1] : v) : bv[q];
                bi[q] = g[q] ? (g[q - 1] ? bi[q - 1] : e) : bi[q];
            }
            if (g[0]) { bv[0] = v; bi[0] = e; }
        }
    }

    const size_t ob = (tb + tid) * TOPK;
#pragma unroll
    for (int q = 0; q < TOPK; ++q) {
        out_w[ob + q] = 1.0f / (1.0f + expf(-bv[q]));
        out_i[ob + q] = (float)bi[q];   // harness reads d_out as float32
    }
}

extern "C" void kernel_launch(void* const* d_in, const int* in_sizes, int n_in,
                              void* d_out, int out_size, void* d_ws, size_t ws_size,
                              hipStream_t stream) {
    const float* x    = (const float*)d_in[0];   // [4,4096,2048]
    const float* W    = (const float*)d_in[1];   // [64,2048]
    const float* bias = (const float*)d_in[2];   // [64]
    float* out_w  = (float*)d_out;                    // [16384,8] weights
    float* out_i  = (float*)d_out + (size_t)TOKENS * TOPK; // [16384,8] indices
    float* logits = (float*)d_ws;                     // 16384*64 fp32 = 4 MiB

    router_gemm<<<TOKENS / BM, 256, 0, stream>>>(x, W, bias, logits);
    router_topk<<<TOKENS / 256, 256, 0, stream>>>(logits, out_w, out_i);
}